// Round 4
// baseline (529.529 us; speedup 1.0000x reference)
//
#include <hip/hip_runtime.h>
#include <hip/hip_bf16.h>
#include <type_traits>

#define N_NODES 50000
#define KK 32
#define EE 128
#define NK (N_NODES * KK)
#define NE (N_NODES * EE)
#define TN 16
#define WAVES 4

typedef __hip_bfloat16 bf16;

__device__ __forceinline__ float b2f(bf16 x) { return __bfloat162float(x); }
__device__ __forceinline__ bf16 f2b(float x) { return __float2bfloat16(x); }

template <bool F32>
__device__ __forceinline__ float ldv(const void* p, long i) {
    if constexpr (F32) return ((const float*)p)[i];
    else               return b2f(((const bf16*)p)[i]);
}
template <bool F32>
__device__ __forceinline__ void stv(void* p, long i, float v) {
    if constexpr (F32) ((float*)p)[i] = v;
    else               ((bf16*)p)[i] = f2b(v);
}

// ---------------------------------------------------------------------------
// Dtype probe: bf16 arrays of ~N(0,1) values have nearly all u16 words with a
// plausible bf16 exponent; f32 arrays read as u16 have random mantissa bits in
// the low halves (~12% plausible) -> ~56% total. Writes flag: 0=bf16, 1=f32.
// ---------------------------------------------------------------------------
__global__ void probe_dtype(const unsigned short* u, int* flag) {
    if (blockIdx.x == 0 && threadIdx.x == 0) {
        int plaus = 0;
        for (int i = 0; i < 512; ++i) {
            int e = (u[i] >> 7) & 0xFF;
            plaus += (e >= 110 && e <= 140) ? 1 : 0;
        }
        *flag = (plaus >= 410) ? 0 : 1;
    }
}

// ---------------------------------------------------------------------------
// Combine weights: A = WhL@Wf, B = WhR@Wf (column-major [c][r]),
// ag = WhL@bf, bh2 = WhR@bf + bh.  grid (128,2), block 128.
// ---------------------------------------------------------------------------
template <bool F32>
__global__ void combine_weights(const int* flag, const void* Wh, const void* Wf,
                                const void* bfv, const void* bh,
                                float* Acm, float* Bcm, float* agf, float* bh2f) {
    if (*flag != (F32 ? 1 : 0)) return;
    int r = blockIdx.x;
    int m = blockIdx.y;
    int c = threadIdx.x;
    long wbase = (long)r * (2 * EE) + m * EE;
    float acc = 0.f;
    for (int j = 0; j < EE; ++j)
        acc += ldv<F32>(Wh, wbase + j) * ldv<F32>(Wf, (long)j * EE + c);
    float* dst = m ? Bcm : Acm;
    dst[c * EE + r] = acc;
    if (c == 0) {
        float accb = 0.f;
        for (int j = 0; j < EE; ++j)
            accb += ldv<F32>(Wh, wbase + j) * ldv<F32>(bfv, j);
        if (m) bh2f[r] = accb + ldv<F32>(bh, r);
        else   agf[r] = accb;
    }
}

// Transpose Ws [128][256] -> Wst [256][128] f32. grid 256, block 128.
template <bool F32>
__global__ void transpose_ws(const int* flag, const void* Ws, float* Wst) {
    if (*flag != (F32 ? 1 : 0)) return;
    int c = blockIdx.x;
    int r = threadIdx.x;
    Wst[c * EE + r] = ldv<F32>(Ws, (long)r * (2 * EE) + c);
}

// ---------------------------------------------------------------------------
// Distance MLP: d(x) = sum_e W2[e]*relu(W1[e]*x + b1[e]) + b2.
// d written into the out_position region of d_out (flag dtype; fused_msg
// reads its own node's d before overwriting with pos).
// ---------------------------------------------------------------------------
template <bool F32>
__global__ __launch_bounds__(256) void dist_mlp(const int* flag, const void* dists,
                                                const void* W1, const void* b1,
                                                const void* W2, const void* b2v,
                                                void* d_out) {
    if (*flag != (F32 ? 1 : 0)) return;
    __shared__ float4 w4[EE];
    int tid = threadIdx.x;
    if (tid < EE)
        w4[tid] = make_float4(ldv<F32>(W1, tid), ldv<F32>(b1, tid), ldv<F32>(W2, tid), 0.f);
    __syncthreads();
    float b2s = ldv<F32>(b2v, 0);
    int i0 = (blockIdx.x * 256 + tid) * 4;
    float x[4], acc[4];
    #pragma unroll
    for (int j = 0; j < 4; ++j) {
        int i = i0 + j;
        x[j] = (i < NK) ? ldv<F32>(dists, i) : 0.f;
        acc[j] = b2s;
    }
    for (int e = 0; e < EE; ++e) {
        float4 w = w4[e];
        #pragma unroll
        for (int j = 0; j < 4; ++j)
            acc[j] += w.z * fmaxf(w.x * x[j] + w.y, 0.f);
    }
    #pragma unroll
    for (int j = 0; j < 4; ++j) {
        int i = i0 + j;
        if (i < NK) stv<F32>(d_out, i, acc[j]);
    }
}

// ---------------------------------------------------------------------------
// g = feature @ A^T + ag, written (flag dtype) into the out_structure region.
// grid N/TN, block 128.
// ---------------------------------------------------------------------------
template <bool F32>
__global__ __launch_bounds__(128) void proj_g(const int* flag, const void* feature,
                                              const float* Acm, const float* agf,
                                              void* d_out) {
    if (*flag != (F32 ? 1 : 0)) return;
    using T = std::conditional_t<F32, float, bf16>;
    T* g = (T*)d_out + NK;
    __shared__ float fl[TN][EE];
    int r = threadIdx.x;
    int n0 = blockIdx.x * TN;
    for (int n = 0; n < TN; ++n)
        fl[n][r] = ldv<F32>(feature, (long)(n0 + n) * EE + r);
    __syncthreads();
    float accg[TN];
    float ag = agf[r];
    #pragma unroll
    for (int n = 0; n < TN; ++n) accg[n] = ag;
    for (int c = 0; c < EE; ++c) {
        float a = Acm[c * EE + r];
        #pragma unroll
        for (int n = 0; n < TN; ++n) accg[n] += fl[n][c] * a;
    }
    for (int n = 0; n < TN; ++n)
        stv<F32>(g, (long)(n0 + n) * EE + r, accg[n]);
}

// ---------------------------------------------------------------------------
// Fused: recompute h2[n] = feature[n]@B^T + bh2 (B bf16 in LDS), then
// gather + relu + Wp-dot + mean. One wave per node, 2 channels/lane.
// d lives in out_position region (own node's values read then overwritten);
// g lives in out_structure region (read-only here). grid N/4, block 256.
// ---------------------------------------------------------------------------
template <bool F32>
__global__ __launch_bounds__(256) void fused_msg(const int* flag, const int* argmax,
                                                 const void* feature,
                                                 const float* Bcm, const float* bh2f,
                                                 const void* Wp, const void* bpv,
                                                 void* d_out, bf16* meanws) {
    if (*flag != (F32 ? 1 : 0)) return;
    using T = std::conditional_t<F32, float, bf16>;
    T* dtab = (T*)d_out;          // [N,K]: d values now, pos after
    T* g    = (T*)d_out + NK;     // [N,E]
    __shared__ bf16 Bl[EE * EE];      // 32 KB
    __shared__ float frow[WAVES][EE]; // 2 KB
    int tid = threadIdx.x;
    int wave = tid >> 6, lane = tid & 63;
    int n = blockIdx.x * WAVES + wave;
    for (int i = tid; i < EE * EE; i += 256)
        Bl[i] = f2b(Bcm[i]);
    frow[wave][lane]      = ldv<F32>(feature, (long)n * EE + lane);
    frow[wave][lane + 64] = ldv<F32>(feature, (long)n * EE + lane + 64);
    __syncthreads();

    int e0 = lane, e1 = lane + 64;
    float h0 = bh2f[e0], h1 = bh2f[e1];
    for (int c = 0; c < EE; ++c) {
        float f = frow[wave][c];
        h0 += f * b2f(Bl[c * EE + e0]);
        h1 += f * b2f(Bl[c * EE + e1]);
    }

    int idxv = 0;
    float dv = 0.f;
    if (lane < KK) {
        idxv = argmax[n * KK + lane];
        dv = ldv<F32>(dtab, (long)n * KK + lane);
    }
    float wp0 = ldv<F32>(Wp, e0), wp1 = ldv<F32>(Wp, e1);
    float bpf = ldv<F32>(bpv, 0);
    float acc0 = 0.f, acc1 = 0.f, pos = 0.f;
    for (int k = 0; k < KK; ++k) {
        int row = __shfl(idxv, k);
        float dk = __shfl(dv, k);
        float g0 = ldv<F32>(g, (long)row * EE + e0);
        float g1 = ldv<F32>(g, (long)row * EE + e1);
        float m0 = fmaxf(dk * g0 + h0, 0.f);
        float m1 = fmaxf(dk * g1 + h1, 0.f);
        acc0 += m0;
        acc1 += m1;
        float p = m0 * wp0 + m1 * wp1;
        #pragma unroll
        for (int off = 32; off; off >>= 1) p += __shfl_xor(p, off);
        if (lane == k) pos = p + bpf;
    }
    if (lane < KK) stv<F32>(dtab, (long)n * KK + lane, pos);
    meanws[(long)n * EE + e0] = f2b(acc0 * (1.f / KK));
    meanws[(long)n * EE + e1] = f2b(acc1 * (1.f / KK));
}

// ---------------------------------------------------------------------------
// out_structure = [mean | edge_attr] @ Ws^T + bs.  Overwrites the
// out_structure region (g dead). grid N/TN, block 128.
// ---------------------------------------------------------------------------
template <bool F32>
__global__ __launch_bounds__(128) void out_struct(const int* flag, const bf16* meanws,
                                                  const void* edge_attr,
                                                  const float* Wst, const void* bs,
                                                  void* d_out) {
    if (*flag != (F32 ? 1 : 0)) return;
    using T = std::conditional_t<F32, float, bf16>;
    T* outs = (T*)d_out + NK;
    __shared__ float mm[TN][EE];
    __shared__ float ea[TN][EE];
    int r = threadIdx.x;
    int n0 = blockIdx.x * TN;
    for (int n = 0; n < TN; ++n) {
        mm[n][r] = b2f(meanws[(long)(n0 + n) * EE + r]);
        ea[n][r] = ldv<F32>(edge_attr, (long)(n0 + n) * EE + r);
    }
    __syncthreads();
    float acc[TN];
    float bsr = ldv<F32>(bs, r);
    #pragma unroll
    for (int n = 0; n < TN; ++n) acc[n] = bsr;
    for (int c = 0; c < EE; ++c) {
        float w = Wst[c * EE + r];
        #pragma unroll
        for (int n = 0; n < TN; ++n) acc[n] += mm[n][c] * w;
    }
    for (int c = 0; c < EE; ++c) {
        float w = Wst[(EE + c) * EE + r];
        #pragma unroll
        for (int n = 0; n < TN; ++n) acc[n] += ea[n][c] * w;
    }
    for (int n = 0; n < TN; ++n)
        stv<F32>(outs, (long)(n0 + n) * EE + r, acc[n]);
}

extern "C" void kernel_launch(void* const* d_in, const int* in_sizes, int n_in,
                              void* d_out, int out_size, void* d_ws, size_t ws_size,
                              hipStream_t stream) {
    const void* feature   = d_in[0];
    const void* dists_max = d_in[1];
    const int* dists_argmax = (const int*)d_in[2];
    const void* edge_attr = d_in[3];
    const void* W1 = d_in[4];
    const void* b1 = d_in[5];
    const void* W2 = d_in[6];
    const void* b2 = d_in[7];
    const void* Wf = d_in[8];
    const void* bf = d_in[9];
    const void* Wh = d_in[10];
    const void* bh = d_in[11];
    const void* Wp = d_in[12];
    const void* bp = d_in[13];
    const void* Ws = d_in[14];
    const void* bs = d_in[15];

    // Workspace: flag(16 f32 pad) + Acm + Bcm + agf + bh2f + Wst (0.26 MB)
    //            + meanws bf16 [N*E] (12.8 MB)  => 13.06 MB total.
    float* wsf  = (float*)d_ws;
    int*   flag = (int*)wsf;
    float* Acm  = wsf + 16;
    float* Bcm  = Acm + EE * EE;
    float* agf  = Bcm + EE * EE;
    float* bh2f = agf + EE;
    float* Wst  = bh2f + EE;
    bf16* meanws = (bf16*)(Wst + 2 * EE * EE);

    probe_dtype<<<1, 64, 0, stream>>>((const unsigned short*)feature, flag);

    combine_weights<false><<<dim3(EE, 2), EE, 0, stream>>>(flag, Wh, Wf, bf, bh, Acm, Bcm, agf, bh2f);
    combine_weights<true ><<<dim3(EE, 2), EE, 0, stream>>>(flag, Wh, Wf, bf, bh, Acm, Bcm, agf, bh2f);
    transpose_ws<false><<<2 * EE, EE, 0, stream>>>(flag, Ws, Wst);
    transpose_ws<true ><<<2 * EE, EE, 0, stream>>>(flag, Ws, Wst);
    dist_mlp<false><<<(NK + 1023) / 1024, 256, 0, stream>>>(flag, dists_max, W1, b1, W2, b2, d_out);
    dist_mlp<true ><<<(NK + 1023) / 1024, 256, 0, stream>>>(flag, dists_max, W1, b1, W2, b2, d_out);
    proj_g<false><<<N_NODES / TN, EE, 0, stream>>>(flag, feature, Acm, agf, d_out);
    proj_g<true ><<<N_NODES / TN, EE, 0, stream>>>(flag, feature, Acm, agf, d_out);
    fused_msg<false><<<N_NODES / WAVES, 256, 0, stream>>>(flag, dists_argmax, feature, Bcm, bh2f, Wp, bp, d_out, meanws);
    fused_msg<true ><<<N_NODES / WAVES, 256, 0, stream>>>(flag, dists_argmax, feature, Bcm, bh2f, Wp, bp, d_out, meanws);
    out_struct<false><<<N_NODES / TN, EE, 0, stream>>>(flag, meanws, edge_attr, Wst, bs, d_out);
    out_struct<true ><<<N_NODES / TN, EE, 0, stream>>>(flag, meanws, edge_attr, Wst, bs, d_out);
}

// Round 5
// 424.620 us; speedup vs baseline: 1.2471x; 1.2471x over previous
//
#include <hip/hip_runtime.h>
#include <hip/hip_bf16.h>

#define N_NODES 50000
#define KK 32
#define EE 128
#define NK (N_NODES * KK)
#define NE (N_NODES * EE)
#define TN 16
#define WAVES 4

typedef __hip_bfloat16 bf16;
typedef unsigned int u32;
typedef unsigned short u16;

// bf16x2 packed in a dword: lo = element 2*lane, hi = element 2*lane+1
__device__ __forceinline__ float bflo(u32 u) { return __uint_as_float(u << 16); }
__device__ __forceinline__ float bfhi(u32 u) { return __uint_as_float(u & 0xFFFF0000u); }
__device__ __forceinline__ u16 f2bu(float x) {
    union { bf16 b; u16 u; } c; c.b = __float2bfloat16(x); return c.u;
}
__device__ __forceinline__ u32 packbf2(float lo, float hi) {
    return (u32)f2bu(lo) | ((u32)f2bu(hi) << 16);
}

// ---------------------------------------------------------------------------
// Combine weights (f32): A = WhL@Wf, B = WhR@Wf (column-major [c][r]),
// ag = WhL@bf, bh2 = WhR@bf + bh.  grid (128,2), block 128.
// ---------------------------------------------------------------------------
__global__ void combine_weights(const float* Wh, const float* Wf, const float* bfv,
                                const float* bh, float* Acm, float* Bcm,
                                float* agf, float* bh2f) {
    int r = blockIdx.x;
    int m = blockIdx.y;
    int c = threadIdx.x;
    const float* whrow = Wh + (long)r * (2 * EE) + m * EE;
    float acc = 0.f;
    for (int j = 0; j < EE; ++j)
        acc += whrow[j] * Wf[(long)j * EE + c];
    float* dst = m ? Bcm : Acm;
    dst[c * EE + r] = acc;
    if (c == 0) {
        float accb = 0.f;
        for (int j = 0; j < EE; ++j) accb += whrow[j] * bfv[j];
        if (m) bh2f[r] = accb + bh[r];
        else   agf[r] = accb;
    }
}

// Transpose Ws [128][256] -> Wst [256][128] f32. grid 256, block 128.
__global__ void transpose_ws(const float* Ws, float* Wst) {
    int c = blockIdx.x;
    int r = threadIdx.x;
    Wst[c * EE + r] = Ws[(long)r * (2 * EE) + c];
}

// ---------------------------------------------------------------------------
// Distance MLP: d(x) = sum_e W2[e]*relu(W1[e]*x + b1[e]) + b2.
// d written f32 into the out_position region of d_out (fused_msg reads its
// own node's d before overwriting with pos).
// ---------------------------------------------------------------------------
__global__ __launch_bounds__(256) void dist_mlp(const float* dists, const float* W1,
                                                const float* b1, const float* W2,
                                                const float* b2v, float* dst) {
    __shared__ float4 w4[EE];
    int tid = threadIdx.x;
    if (tid < EE) w4[tid] = make_float4(W1[tid], b1[tid], W2[tid], 0.f);
    __syncthreads();
    float b2s = b2v[0];
    int i0 = (blockIdx.x * 256 + tid) * 4;
    float x[4], acc[4];
    #pragma unroll
    for (int j = 0; j < 4; ++j) {
        int i = i0 + j;
        x[j] = (i < NK) ? dists[i] : 0.f;
        acc[j] = b2s;
    }
    for (int e = 0; e < EE; ++e) {
        float4 w = w4[e];
        #pragma unroll
        for (int j = 0; j < 4; ++j)
            acc[j] += w.z * fmaxf(w.x * x[j] + w.y, 0.f);
    }
    #pragma unroll
    for (int j = 0; j < 4; ++j) {
        int i = i0 + j;
        if (i < NK) dst[i] = acc[j];
    }
}

// ---------------------------------------------------------------------------
// g = feature@A^T + ag, h2 = feature@B^T + bh2, both bf16, packed into the
// out_structure region of d_out (g then h2, 12.8 MB each).
// Register-blocked over TN=16 nodes. grid N/TN, block 128.
// ---------------------------------------------------------------------------
__global__ __launch_bounds__(128) void proj_gh(const float* feature, const float* Acm,
                                               const float* Bcm, const float* agf,
                                               const float* bh2f, u16* g, u16* h2) {
    __shared__ float fl[TN][EE];
    int r = threadIdx.x;
    int n0 = blockIdx.x * TN;
    for (int n = 0; n < TN; ++n)
        fl[n][r] = feature[(long)(n0 + n) * EE + r];
    __syncthreads();
    float accg[TN], acch[TN];
    float ag = agf[r], bh = bh2f[r];
    #pragma unroll
    for (int n = 0; n < TN; ++n) { accg[n] = ag; acch[n] = bh; }
    for (int c = 0; c < EE; ++c) {
        float a = Acm[c * EE + r];
        float b = Bcm[c * EE + r];
        #pragma unroll
        for (int n = 0; n < TN; ++n) {
            float f = fl[n][c];
            accg[n] += f * a;
            acch[n] += f * b;
        }
    }
    for (int n = 0; n < TN; ++n) {
        g [(long)(n0 + n) * EE + r] = f2bu(accg[n]);
        h2[(long)(n0 + n) * EE + r] = f2bu(acch[n]);
    }
}

// ---------------------------------------------------------------------------
// Fused gather + relu + Wp-dot + mean. One wave per node; lane handles
// channels (2*lane, 2*lane+1) so each gather is ONE dword (bf16x2).
// No LDS -> occupancy limited only by VGPRs. grid N/4, block 256.
// ---------------------------------------------------------------------------
__global__ __launch_bounds__(256) void fused_msg(const int* argmax, const u32* g,
                                                 const u32* h2, const float* Wp,
                                                 const float* bpv,
                                                 float* outpos, u32* meanws) {
    int tid = threadIdx.x;
    int wave = tid >> 6, lane = tid & 63;
    int n = blockIdx.x * WAVES + wave;

    u32 hu = h2[(long)n * (EE / 2) + lane];
    float h0 = bflo(hu), h1 = bfhi(hu);
    float2 wpv = ((const float2*)Wp)[lane];
    float bpf = bpv[0];

    int idxv = 0;
    float dv = 0.f;
    if (lane < KK) {
        idxv = argmax[(long)n * KK + lane];
        dv = outpos[(long)n * KK + lane];   // d (written by dist_mlp)
    }
    float acc0 = 0.f, acc1 = 0.f, pos = 0.f;
    #pragma unroll 4
    for (int k = 0; k < KK; ++k) {
        int row = __shfl(idxv, k);
        float dk = __shfl(dv, k);
        u32 gu = g[(long)row * (EE / 2) + lane];
        float m0 = fmaxf(dk * bflo(gu) + h0, 0.f);
        float m1 = fmaxf(dk * bfhi(gu) + h1, 0.f);
        acc0 += m0;
        acc1 += m1;
        float p = m0 * wpv.x + m1 * wpv.y;
        #pragma unroll
        for (int off = 32; off; off >>= 1) p += __shfl_xor(p, off);
        if (lane == k) pos = p + bpf;
    }
    if (lane < KK) outpos[(long)n * KK + lane] = pos;
    meanws[(long)n * (EE / 2) + lane] = packbf2(acc0 * (1.f / KK), acc1 * (1.f / KK));
}

// ---------------------------------------------------------------------------
// out_structure = [mean | edge_attr] @ Ws^T + bs -> f32, overwrites the
// out_structure region (g/h2 dead). grid N/TN, block 128.
// ---------------------------------------------------------------------------
__global__ __launch_bounds__(128) void out_struct(const u16* meanws, const float* edge_attr,
                                                  const float* Wst, const float* bs,
                                                  float* outs) {
    __shared__ float mm[TN][EE];
    __shared__ float ea[TN][EE];
    int r = threadIdx.x;
    int n0 = blockIdx.x * TN;
    for (int n = 0; n < TN; ++n) {
        union { bf16 b; u16 u; } c; c.u = meanws[(long)(n0 + n) * EE + r];
        mm[n][r] = __bfloat162float(c.b);
        ea[n][r] = edge_attr[(long)(n0 + n) * EE + r];
    }
    __syncthreads();
    float acc[TN];
    float bsr = bs[r];
    #pragma unroll
    for (int n = 0; n < TN; ++n) acc[n] = bsr;
    for (int c = 0; c < EE; ++c) {
        float w = Wst[c * EE + r];
        #pragma unroll
        for (int n = 0; n < TN; ++n) acc[n] += mm[n][c] * w;
    }
    for (int c = 0; c < EE; ++c) {
        float w = Wst[(EE + c) * EE + r];
        #pragma unroll
        for (int n = 0; n < TN; ++n) acc[n] += ea[n][c] * w;
    }
    for (int n = 0; n < TN; ++n)
        outs[(long)(n0 + n) * EE + r] = acc[n];
}

extern "C" void kernel_launch(void* const* d_in, const int* in_sizes, int n_in,
                              void* d_out, int out_size, void* d_ws, size_t ws_size,
                              hipStream_t stream) {
    const float* feature   = (const float*)d_in[0];
    const float* dists_max = (const float*)d_in[1];
    const int* dists_argmax = (const int*)d_in[2];
    const float* edge_attr = (const float*)d_in[3];
    const float* W1 = (const float*)d_in[4];
    const float* b1 = (const float*)d_in[5];
    const float* W2 = (const float*)d_in[6];
    const float* b2 = (const float*)d_in[7];
    const float* Wf = (const float*)d_in[8];
    const float* bf = (const float*)d_in[9];
    const float* Wh = (const float*)d_in[10];
    const float* bh = (const float*)d_in[11];
    const float* Wp = (const float*)d_in[12];
    const float* bp = (const float*)d_in[13];
    const float* Ws = (const float*)d_in[14];
    const float* bs = (const float*)d_in[15];

    float* outpos = (float*)d_out;        // [N,K] f32: d scratch, then pos
    float* outs   = outpos + NK;          // [N,E] f32: g+h2 bf16 scratch, then out_structure
    u16* g  = (u16*)outs;                 // [N,E] bf16  (12.8 MB)
    u16* h2 = g + NE;                     // [N,E] bf16  (12.8 MB) — exactly fills region

    // Workspace (proven size): 0.26 MB f32 weights + 12.8 MB bf16 mean.
    float* Acm  = (float*)d_ws;           // [EE*EE]
    float* Bcm  = Acm + EE * EE;          // [EE*EE]
    float* agf  = Bcm + EE * EE;          // [EE]
    float* bh2f = agf + EE;               // [EE]
    float* Wst  = bh2f + EE;              // [2*EE*EE]
    u16* meanws = (u16*)(Wst + 2 * EE * EE);  // [N*E] bf16

    combine_weights<<<dim3(EE, 2), EE, 0, stream>>>(Wh, Wf, bf, bh, Acm, Bcm, agf, bh2f);
    transpose_ws<<<2 * EE, EE, 0, stream>>>(Ws, Wst);
    dist_mlp<<<(NK + 1023) / 1024, 256, 0, stream>>>(dists_max, W1, b1, W2, b2, outpos);
    proj_gh<<<N_NODES / TN, EE, 0, stream>>>(feature, Acm, Bcm, agf, bh2f, g, h2);
    fused_msg<<<N_NODES / WAVES, 256, 0, stream>>>(dists_argmax, (const u32*)g,
                                                   (const u32*)h2, Wp, bp,
                                                   outpos, (u32*)meanws);
    out_struct<<<N_NODES / TN, EE, 0, stream>>>(meanws, edge_attr, Wst, bs, outs);
}